// Round 19
// baseline (99.837 us; speedup 1.0000x reference)
//
#include <hip/hip_runtime.h>
#include <math.h>

#define FDIM 128
#define NP 64                 // CSR partition blocks
#define NMAX 10240            // LDS capacity (N=10000)
static constexpr float SC2 = 0.17677669529663687f * 1.4426950408889634f; // (1/sqrt(32))*log2(e)
static constexpr float LN_EPS = 1e-5f;

typedef __attribute__((ext_vector_type(8))) short bf16x8;
typedef __attribute__((ext_vector_type(4))) float f32x4;

__device__ __forceinline__ unsigned short f2bf(float f) {
    unsigned u = __float_as_uint(f);
    unsigned r = u + 0x7FFFu + ((u >> 16) & 1u);   // RNE
    return (unsigned short)(r >> 16);
}

// ---------------------------------------------------------------------------
// L1: prep (blocks 0..15) || histogram+rank (blocks 16..16+NP-1).
// prep: W f32 -> W^T bf16. hist: bh[p*N+d] counts AND rank[e] (LDS atomic
// return). Block 0 also zeroes the device-sync counter for L2.
// ---------------------------------------------------------------------------
__global__ __launch_bounds__(256) void prep_hist_kernel(
    const float* __restrict__ Wq, const float* __restrict__ Wk,
    const float* __restrict__ Wv, const float* __restrict__ Wr,
    unsigned short* __restrict__ Wt,
    const int* __restrict__ dst, int* __restrict__ bh,
    int* __restrict__ rank, int* __restrict__ done,
    int N, int E, int C)
{
    __shared__ int h[NMAX];
    const int tid = threadIdx.x;
    const int b = blockIdx.x;

    if (b < 16) {                     // ---- prep partition ----
        if (b == 0 && tid == 0) *done = 0;
        const int wiW = b >> 2, q = b & 3;
        const float* __restrict__ W = (wiW == 0) ? Wq : (wiW == 1) ? Wk : (wiW == 2) ? Wv : Wr;
        const int c = q * 32 + (tid >> 3);
        const int k0 = (tid & 7) * 16;
        unsigned short* dp = &Wt[(size_t)wiW * 16384 + c * 128 + k0];
        #pragma unroll
        for (int kk = 0; kk < 16; ++kk)
            dp[kk] = f2bf(W[(k0 + kk) * FDIM + c]);
        return;
    }

    // ---- histogram partition ----
    const int p = b - 16;
    if (p >= NP) return;
    for (int i = tid; i < N; i += 256) h[i] = 0;
    __syncthreads();
    const int lo = p * C;
    const int hi = min(lo + C, E);
    const int n = hi - lo;
    if (n > 0) {
        if (((lo | E) & 3) == 0) {
            const int4* d4 = (const int4*)(dst + lo);
            int4* r4p = (int4*)(rank + lo);
            const int n4 = n >> 2;
            for (int i = tid; i < n4; i += 256) {
                int4 d = d4[i];
                int4 r;
                r.x = atomicAdd(&h[d.x], 1);
                r.y = atomicAdd(&h[d.y], 1);
                r.z = atomicAdd(&h[d.z], 1);
                r.w = atomicAdd(&h[d.w], 1);
                r4p[i] = r;
            }
            for (int i = lo + (n4 << 2) + tid; i < hi; i += 256)
                rank[i] = atomicAdd(&h[dst[i]], 1);
        } else {
            for (int i = lo + tid; i < hi; i += 256)
                rank[i] = atomicAdd(&h[dst[i]], 1);
        }
    }
    __syncthreads();
    for (int i = tid; i < N; i += 256) bh[p * N + i] = h[i];
}

// ---------------------------------------------------------------------------
// L2: degrel + scan fused (last-block pattern).
// Phase A (all blocks): deg[d] = sum_p bh[p][d]; bh -> partition-relative
// exclusive bases, in place. Phase B (last-arriving block): exclusive scan
// of deg -> rowptr (256-thread shuffle scan).
// ---------------------------------------------------------------------------
__global__ __launch_bounds__(256) void degrel_scan_kernel(
    int* __restrict__ bh, int* __restrict__ deg, int* __restrict__ rowptr,
    int* __restrict__ done, int N)
{
    __shared__ int wsum[4];
    __shared__ int lastFlag;
    const int tid = threadIdx.x;
    const int d = blockIdx.x * 256 + tid;

    if (d < N) {
        int c = 0;
        #pragma unroll
        for (int p = 0; p < NP; ++p) {
            const int cnt = bh[p * N + d];
            bh[p * N + d] = c;
            c += cnt;
        }
        deg[d] = c;
    }

    __threadfence();
    if (tid == 0) {
        const int old = atomicAdd(done, 1);
        lastFlag = (old == (int)gridDim.x - 1);
    }
    __syncthreads();
    if (!lastFlag) return;
    __threadfence();

    // ---- scan (single block, 256 threads) ----
    const int lane = tid & 63;
    const int wid = tid >> 6;
    const int CH = (N + 255) / 256;
    const int b0 = tid * CH;
    const int e0 = min(b0 + CH, N);
    int s = 0;
    for (int i = b0; i < e0; ++i) s += deg[i];

    int incl = s;
    #pragma unroll
    for (int off = 1; off < 64; off <<= 1) {
        int t = __shfl_up(incl, off);
        if (lane >= off) incl += t;
    }
    if (lane == 63) wsum[wid] = incl;
    __syncthreads();
    if (wid == 0) {
        int v = (lane < 4) ? wsum[lane] : 0;
        #pragma unroll
        for (int off = 1; off < 4; off <<= 1) {
            int t = __shfl_up(v, off);
            if (lane >= off) v += t;
        }
        if (lane < 4) wsum[lane] = v;
    }
    __syncthreads();
    const int wbase = (wid > 0) ? wsum[wid - 1] : 0;
    int run = wbase + incl - s;
    for (int i = b0; i < e0; ++i) {
        rowptr[i] = run;
        run += deg[i];
    }
    if (tid == 255) rowptr[N] = wsum[3];
}

// ---------------------------------------------------------------------------
// L3: gemm (blockIdx.y 1..4, x<nG) || cursor-free scatter (y==0, x<NP*8).
// GEMM: As (64x128 f32->bf16 inline) + W^T (pre-transposed, vector staged);
// mfma_f32_16x16x32_bf16; C/D col=lane&15, row=(lane>>4)*4+reg (m89).
// Scatter: ssrc[rowptr[d] + rel[p][d] + rank[e]] = src[e]; no atomics.
// ---------------------------------------------------------------------------
__global__ __launch_bounds__(256) void gemm_scatter_kernel(
    const float* __restrict__ nodes,
    const unsigned short* __restrict__ Wt,
    const float* __restrict__ br,
    unsigned short* __restrict__ Qu, unsigned short* __restrict__ KVu,
    float* __restrict__ Rb, int N, int nG,
    const int* __restrict__ src, const int* __restrict__ dst,
    const int* __restrict__ rank, const int* __restrict__ rel,
    const int* __restrict__ rowptr, int* __restrict__ ssrc, int E, int C)
{
    __shared__ __align__(16) char smem[52224];   // 17408 (As) + 34816 (Ws)
    const int tid = threadIdx.x;
    const int wi = blockIdx.y;

    if (wi == 0) {                    // ---- scatter partition ----
        const int p = blockIdx.x >> 3;
        const int sub = blockIdx.x & 7;
        const int CS = C >> 3;
        const int lo = p * C + sub * CS;
        const int hi = min(lo + CS, E);
        const int n = hi - lo;
        if (n <= 0) return;
        const int* rp = &rel[p * N];

        if (((lo | E) & 3) == 0) {
            const int4* s4 = (const int4*)(src + lo);
            const int4* d4 = (const int4*)(dst + lo);
            const int4* r4 = (const int4*)(rank + lo);
            const int n4 = n >> 2;
            for (int i = tid; i < n4; i += 256) {
                const int4 s = s4[i];
                const int4 d = d4[i];
                const int4 r = r4[i];
                ssrc[rowptr[d.x] + rp[d.x] + r.x] = s.x;
                ssrc[rowptr[d.y] + rp[d.y] + r.y] = s.y;
                ssrc[rowptr[d.z] + rp[d.z] + r.z] = s.z;
                ssrc[rowptr[d.w] + rp[d.w] + r.w] = s.w;
            }
            for (int i = lo + (n4 << 2) + tid; i < hi; i += 256)
                ssrc[rowptr[dst[i]] + rp[dst[i]] + rank[i]] = src[i];
        } else {
            for (int i = lo + tid; i < hi; i += 256)
                ssrc[rowptr[dst[i]] + rp[dst[i]] + rank[i]] = src[i];
        }
        return;
    }

    // ---- GEMM partition ----
    if ((int)blockIdx.x >= nG) return;
    const int gw = wi - 1;            // 0=Q, 1=K, 2=V, 3=R
    const int row0 = blockIdx.x * 64;
    unsigned short (*As)[136] = (unsigned short(*)[136])smem;
    unsigned short (*Ws)[136] = (unsigned short(*)[136])(smem + 64 * 272);

    #pragma unroll
    for (int i = 0; i < 8; ++i) {
        const int idx = tid + i * 256;
        const int r = idx >> 5, c4 = idx & 31;
        const int gr = row0 + r;
        float4 v = make_float4(0.f, 0.f, 0.f, 0.f);
        if (gr < N) v = *reinterpret_cast<const float4*>(&nodes[(size_t)gr * FDIM + c4 * 4]);
        ushort4 o;
        o.x = f2bf(v.x); o.y = f2bf(v.y); o.z = f2bf(v.z); o.w = f2bf(v.w);
        *reinterpret_cast<ushort4*>(&As[r][c4 * 4]) = o;
    }
    const unsigned short* Wg = &Wt[(size_t)gw * 16384];
    #pragma unroll
    for (int i = 0; i < 8; ++i) {
        const int idx = tid + i * 256;
        const int r = idx >> 4, ch = idx & 15;
        const uint4 v = *reinterpret_cast<const uint4*>(&Wg[r * 128 + ch * 8]);
        *reinterpret_cast<uint4*>(&Ws[r][ch * 8]) = v;
    }
    __syncthreads();

    const int w = tid >> 6;
    const int l = tid & 63;
    const int lr = l & 15;
    const int lh = l >> 4;

    f32x4 acc[8];
    #pragma unroll
    for (int ct = 0; ct < 8; ++ct) acc[ct] = (f32x4){0.f, 0.f, 0.f, 0.f};

    #pragma unroll
    for (int kc = 0; kc < 4; ++kc) {
        const bf16x8 a = *reinterpret_cast<const bf16x8*>(&As[w * 16 + lr][kc * 32 + lh * 8]);
        #pragma unroll
        for (int ct = 0; ct < 8; ++ct) {
            const bf16x8 bb = *reinterpret_cast<const bf16x8*>(&Ws[ct * 16 + lr][kc * 32 + lh * 8]);
            acc[ct] = __builtin_amdgcn_mfma_f32_16x16x32_bf16(a, bb, acc[ct], 0, 0, 0);
        }
    }

    const int rbase = row0 + w * 16 + lh * 4;
    #pragma unroll
    for (int ct = 0; ct < 8; ++ct) {
        const int col = ct * 16 + lr;
        float bc = 0.f;
        if (gw == 3) bc = br[col];
        #pragma unroll
        for (int r = 0; r < 4; ++r) {
            const int row = rbase + r;
            if (row >= N) continue;
            const float val = acc[ct][r];
            if (gw == 0)      Qu[(size_t)row * 128 + col] = f2bf(val);
            else if (gw == 1) KVu[(size_t)row * 256 + col] = f2bf(val);
            else if (gw == 2) KVu[(size_t)row * 256 + 128 + col] = f2bf(val);
            else              Rb[(size_t)row * 128 + col] = val + bc;
        }
    }
}

// ---------------------------------------------------------------------------
// L4: EDGE-SPLIT agg. Two quarter-waves per node, LDS partial-sum merge,
// s=0 does residual + LayerNorm. Block = 8 nodes x 2 splits x 16 lanes.
// ---------------------------------------------------------------------------
__global__ __launch_bounds__(256) void agg_kernel(
    const unsigned short* __restrict__ Qu, const unsigned short* __restrict__ KVu,
    const float* __restrict__ Rb,
    const int* __restrict__ rowptr, const int* __restrict__ ssrc,
    const float* __restrict__ gamma, const float* __restrict__ beta,
    float* __restrict__ out, int N)
{
    __shared__ float sA[8][16][8];
    __shared__ float sL[8][16];

    const int wave = threadIdx.x >> 6;
    const int lane = threadIdx.x & 63;
    const int qtr = lane >> 4;
    const int lq = lane & 15;
    const int slot = wave * 2 + (qtr >> 1);
    const int s = qtr & 1;
    const int n = blockIdx.x * 8 + slot;
    const bool active = (n < N);
    const int d0 = lq * 8;

    uint4 qu = make_uint4(0u, 0u, 0u, 0u);
    int beg = 0, end = 0;
    if (active) {
        qu = *reinterpret_cast<const uint4*>(&Qu[(size_t)n * 128 + d0]);
        beg = rowptr[n];
        end = rowptr[n + 1];
    }
    const float qf0 = __uint_as_float(qu.x << 16), qf1 = __uint_as_float(qu.x & 0xFFFF0000u);
    const float qf2 = __uint_as_float(qu.y << 16), qf3 = __uint_as_float(qu.y & 0xFFFF0000u);
    const float qf4 = __uint_as_float(qu.z << 16), qf5 = __uint_as_float(qu.z & 0xFFFF0000u);
    const float qf6 = __uint_as_float(qu.w << 16), qf7 = __uint_as_float(qu.w & 0xFFFF0000u);

    const int nbAll = (end - beg) >> 2;
    const int nbh = (nbAll + 1) >> 1;
    const int b0 = (s == 0) ? 0 : nbh;
    const int b1 = (s == 0) ? nbh : nbAll;
    const int j0 = beg + b0 * 4;
    const int m = b1 - b0;

    float4 A0a = make_float4(0.f, 0.f, 0.f, 0.f), A0b = A0a;
    float4 A1a = A0a, A1b = A0a, A2a = A0a, A2b = A0a, A3a = A0a, A3b = A0a;
    float L0 = 0.f, L1 = 0.f, L2 = 0.f, L3 = 0.f;

#define GATHER(S, NK, NV)                                                     \
    {                                                                         \
        const unsigned short* bp = &KVu[(size_t)(S) * 256 + d0];              \
        NK = *reinterpret_cast<const uint4*>(bp);                             \
        NV = *reinterpret_cast<const uint4*>(bp + 128);                       \
    }
#define STEP(KU, VU, Aa, Ab, L)                                               \
    {                                                                         \
        const float k0 = __uint_as_float((KU).x << 16), k1 = __uint_as_float((KU).x & 0xFFFF0000u); \
        const float k2 = __uint_as_float((KU).y << 16), k3 = __uint_as_float((KU).y & 0xFFFF0000u); \
        const float k4 = __uint_as_float((KU).z << 16), k5 = __uint_as_float((KU).z & 0xFFFF0000u); \
        const float k6 = __uint_as_float((KU).w << 16), k7 = __uint_as_float((KU).w & 0xFFFF0000u); \
        float p = qf0 * k0 + qf1 * k1 + qf2 * k2 + qf3 * k3                   \
                + qf4 * k4 + qf5 * k5 + qf6 * k6 + qf7 * k7;                  \
        p += __shfl_xor(p, 1);                                                \
        p += __shfl_xor(p, 2);                                                \
        const float e1 = exp2f(p * SC2);                                      \
        const float v0 = __uint_as_float((VU).x << 16), v1 = __uint_as_float((VU).x & 0xFFFF0000u); \
        const float v2 = __uint_as_float((VU).y << 16), v3 = __uint_as_float((VU).y & 0xFFFF0000u); \
        const float v4 = __uint_as_float((VU).z << 16), v5 = __uint_as_float((VU).z & 0xFFFF0000u); \
        const float v6 = __uint_as_float((VU).w << 16), v7 = __uint_as_float((VU).w & 0xFFFF0000u); \
        Aa.x += e1 * v0; Aa.y += e1 * v1; Aa.z += e1 * v2; Aa.w += e1 * v3;   \
        Ab.x += e1 * v4; Ab.y += e1 * v5; Ab.z += e1 * v6; Ab.w += e1 * v7;   \
        L += e1;                                                              \
    }

    uint4 nk0, nv0, nk1, nv1, nk2, nv2, nk3, nv3;
    if (m > 0) {
        int c0i = ssrc[j0], c1i = ssrc[j0 + 1], c2i = ssrc[j0 + 2], c3i = ssrc[j0 + 3];
        GATHER(c0i, nk0, nv0); GATHER(c1i, nk1, nv1);
        GATHER(c2i, nk2, nv2); GATHER(c3i, nk3, nv3);
        int x0 = ssrc[j0 + 4], x1 = ssrc[j0 + 5], x2 = ssrc[j0 + 6], x3 = ssrc[j0 + 7];
        for (int bi = 1; bi < m; ++bi) {
            const uint4 ck0 = nk0, cv0 = nv0, ck1 = nk1, cv1 = nv1;
            const uint4 ck2 = nk2, cv2 = nv2, ck3 = nk3, cv3 = nv3;
            c0i = x0; c1i = x1; c2i = x2; c3i = x3;
            const int nbase = j0 + (bi + 1) * 4;
            x0 = ssrc[nbase]; x1 = ssrc[nbase + 1];
            x2 = ssrc[nbase + 2]; x3 = ssrc[nbase + 3];
            GATHER(c0i, nk0, nv0); GATHER(c1i, nk1, nv1);
            GATHER(c2i, nk2, nv2); GATHER(c3i, nk3, nv3);
            STEP(ck0, cv0, A0a, A0b, L0);
            STEP(ck1, cv1, A1a, A1b, L1);
            STEP(ck2, cv2, A2a, A2b, L2);
            STEP(ck3, cv3, A3a, A3b, L3);
        }
        STEP(nk0, nv0, A0a, A0b, L0);
        STEP(nk1, nv1, A1a, A1b, L1);
        STEP(nk2, nv2, A2a, A2b, L2);
        STEP(nk3, nv3, A3a, A3b, L3);
    }
    if (s == 1) {
        for (int j = beg + nbAll * 4; j < end; ++j) {
            const int s0 = ssrc[j];
            uint4 k0u, v0u;
            GATHER(s0, k0u, v0u);
            STEP(k0u, v0u, A0a, A0b, L0);
        }
    }
#undef GATHER
#undef STEP

    float a0 = (A0a.x + A1a.x) + (A2a.x + A3a.x);
    float a1 = (A0a.y + A1a.y) + (A2a.y + A3a.y);
    float a2 = (A0a.z + A1a.z) + (A2a.z + A3a.z);
    float a3 = (A0a.w + A1a.w) + (A2a.w + A3a.w);
    float a4 = (A0b.x + A1b.x) + (A2b.x + A3b.x);
    float a5 = (A0b.y + A1b.y) + (A2b.y + A3b.y);
    float a6 = (A0b.z + A1b.z) + (A2b.z + A3b.z);
    float a7 = (A0b.w + A1b.w) + (A2b.w + A3b.w);
    float L = (L0 + L1) + (L2 + L3);

    if (s == 1) {
        float* dp = &sA[slot][lq][0];
        dp[0] = a0; dp[1] = a1; dp[2] = a2; dp[3] = a3;
        dp[4] = a4; dp[5] = a5; dp[6] = a6; dp[7] = a7;
        sL[slot][lq] = L;
    }
    __syncthreads();
    if (s == 1 || !active) return;

    {
        const float* dp = &sA[slot][lq][0];
        a0 += dp[0]; a1 += dp[1]; a2 += dp[2]; a3 += dp[3];
        a4 += dp[4]; a5 += dp[5]; a6 += dp[6]; a7 += dp[7];
        L += sL[slot][lq];
    }

    const float inv = 1.f / (L + 1e-12f);
    const float4 ra = *reinterpret_cast<const float4*>(&Rb[(size_t)n * 128 + d0]);
    const float4 rb = *reinterpret_cast<const float4*>(&Rb[(size_t)n * 128 + d0 + 4]);
    float xa0 = a0 * inv + ra.x;
    float xa1 = a1 * inv + ra.y;
    float xa2 = a2 * inv + ra.z;
    float xa3 = a3 * inv + ra.w;
    float xb0 = a4 * inv + rb.x;
    float xb1 = a5 * inv + rb.y;
    float xb2 = a6 * inv + rb.z;
    float xb3 = a7 * inv + rb.w;

    float s1v = (xa0 + xa1 + xa2 + xa3) + (xb0 + xb1 + xb2 + xb3);
    float s2v = xa0 * xa0 + xa1 * xa1 + xa2 * xa2 + xa3 * xa3
              + xb0 * xb0 + xb1 * xb1 + xb2 * xb2 + xb3 * xb3;
    #pragma unroll
    for (int off = 8; off; off >>= 1) {
        s1v += __shfl_xor(s1v, off);
        s2v += __shfl_xor(s2v, off);
    }
    const float mu = s1v * (1.f / 128.f);
    float var = s2v * (1.f / 128.f) - mu * mu;
    var = fmaxf(var, 0.f);
    const float rs = rsqrtf(var + LN_EPS);

    const float4 ga = *reinterpret_cast<const float4*>(&gamma[d0]);
    const float4 gb = *reinterpret_cast<const float4*>(&gamma[d0 + 4]);
    const float4 ba = *reinterpret_cast<const float4*>(&beta[d0]);
    const float4 bb = *reinterpret_cast<const float4*>(&beta[d0 + 4]);
    float4 oa, ob;
    oa.x = ga.x * (xa0 - mu) * rs + ba.x;
    oa.y = ga.y * (xa1 - mu) * rs + ba.y;
    oa.z = ga.z * (xa2 - mu) * rs + ba.z;
    oa.w = ga.w * (xa3 - mu) * rs + ba.w;
    ob.x = gb.x * (xb0 - mu) * rs + bb.x;
    ob.y = gb.y * (xb1 - mu) * rs + bb.y;
    ob.z = gb.z * (xb2 - mu) * rs + bb.z;
    ob.w = gb.w * (xb3 - mu) * rs + bb.w;
    *reinterpret_cast<float4*>(&out[(size_t)n * 128 + d0]) = oa;
    *reinterpret_cast<float4*>(&out[(size_t)n * 128 + d0 + 4]) = ob;
}

// ---------------------------------------------------------------------------
extern "C" void kernel_launch(void* const* d_in, const int* in_sizes, int n_in,
                              void* d_out, int out_size, void* d_ws, size_t ws_size,
                              hipStream_t stream)
{
    const float* nodes = (const float*)d_in[0];
    const float* W_Q   = (const float*)d_in[1];
    const float* W_K   = (const float*)d_in[2];
    const float* W_V   = (const float*)d_in[3];
    const float* W_res = (const float*)d_in[4];
    const float* b_res = (const float*)d_in[5];
    const float* gamma = (const float*)d_in[6];
    const float* beta  = (const float*)d_in[7];
    const int*   eidx  = (const int*)d_in[8];

    const int N = in_sizes[0] / FDIM;
    const int E = in_sizes[8] / 2;
    const int* src = eidx;
    const int* dst = eidx + E;

    float* out = (float*)d_out;

    // workspace carve
    unsigned short* KVu = (unsigned short*)d_ws;              // N*256 bf16
    unsigned short* Qu  = KVu + (size_t)N * 256;              // N*128 bf16
    unsigned short* Wt  = Qu + (size_t)N * 128;               // 4*128*128 bf16
    float* Rb   = (float*)(Wt + 4 * 16384);                   // N*128 f32
    int* bh     = (int*)(Rb + (size_t)N * 128);               // NP*N (counts -> rel bases)
    int* rowptr = bh + (size_t)NP * N;                        // N+1
    int* deg    = rowptr + (N + 1);                           // N
    int* rank   = deg + N;                                    // E
    int* ssrc   = rank + E;                                   // E + 8
    int* done   = ssrc + E + 8;                               // 1

    const int C = (((E + NP - 1) / NP) + 31) & ~31;           // chunk, mult of 32
    const int nG = (N + 63) / 64;
    const int nB = (N + 255) / 256;

    prep_hist_kernel<<<16 + NP, 256, 0, stream>>>(W_Q, W_K, W_V, W_res, Wt,
                                                  dst, bh, rank, done, N, E, C);
    degrel_scan_kernel<<<nB, 256, 0, stream>>>(bh, deg, rowptr, done, N);

    dim3 ggrid(NP * 8, 5);                                    // y==0 -> scatter
    gemm_scatter_kernel<<<ggrid, 256, 0, stream>>>(nodes, Wt, b_res,
                                                   Qu, KVu, Rb, N, nG,
                                                   src, dst, rank, bh, rowptr,
                                                   ssrc, E, C);
    agg_kernel<<<(N + 7) / 8, 256, 0, stream>>>(Qu, KVu, Rb, rowptr, ssrc,
                                                gamma, beta, out, N);
}

// Round 20
// 89.196 us; speedup vs baseline: 1.1193x; 1.1193x over previous
//
#include <hip/hip_runtime.h>
#include <math.h>

#define FDIM 128
#define NP 64                 // CSR partition blocks
#define NMAX 10240            // LDS capacity (N=10000)
static constexpr float SC2 = 0.17677669529663687f * 1.4426950408889634f; // (1/sqrt(32))*log2(e)
static constexpr float LN_EPS = 1e-5f;

typedef __attribute__((ext_vector_type(8))) short bf16x8;
typedef __attribute__((ext_vector_type(4))) float f32x4;

__device__ __forceinline__ unsigned short f2bf(float f) {
    unsigned u = __float_as_uint(f);
    unsigned r = u + 0x7FFFu + ((u >> 16) & 1u);   // RNE
    return (unsigned short)(r >> 16);
}

// ---------------------------------------------------------------------------
// K0: prep — W_{Q,K,V,res} f32 -> W^T bf16 (Wt[wi][c][k]). 16 blocks, ~1us.
// ---------------------------------------------------------------------------
__global__ __launch_bounds__(256) void prep_kernel(
    const float* __restrict__ Wq, const float* __restrict__ Wk,
    const float* __restrict__ Wv, const float* __restrict__ Wr,
    unsigned short* __restrict__ Wt)
{
    const int tid = threadIdx.x;
    const int t = blockIdx.x;           // 0..15
    const int wiW = t >> 2, q = t & 3;
    const float* __restrict__ W = (wiW == 0) ? Wq : (wiW == 1) ? Wk : (wiW == 2) ? Wv : Wr;
    const int c = q * 32 + (tid >> 3);  // 0..127
    const int k0 = (tid & 7) * 16;
    unsigned short* dp = &Wt[(size_t)wiW * 16384 + c * 128 + k0];
    #pragma unroll
    for (int kk = 0; kk < 16; ++kk)
        dp[kk] = f2bf(W[(k0 + kk) * FDIM + c]);
}

// ---------------------------------------------------------------------------
// K1: fused MFMA GEMM (blockIdx.y 1..4) + LDS histogram + rank (y==0, x<NP).
// GEMM: As (64x128 f32->bf16 inline) + W^T (pre-transposed bf16, vector
// staged); mfma_f32_16x16x32_bf16; C/D col=lane&15, row=(lane>>4)*4+reg.
// Hist: bh[p*N+d] counts AND rank[e] (LDS atomicAdd return).
// ---------------------------------------------------------------------------
__global__ __launch_bounds__(256) void gemm_hist_kernel(
    const float* __restrict__ nodes,
    const unsigned short* __restrict__ Wt,
    const float* __restrict__ br,
    unsigned short* __restrict__ Qu, unsigned short* __restrict__ KVu,
    float* __restrict__ Rb, int N,
    const int* __restrict__ dst, int* __restrict__ bh,
    int* __restrict__ rank, int E, int C)
{
    __shared__ __align__(16) char smem[52224];   // max(hist 40960, 17408+34816)
    const int tid = threadIdx.x;
    const int wi = blockIdx.y;

    if (wi == 0) {                    // ---- histogram partition ----
        const int p = blockIdx.x;
        if (p >= NP) return;
        int* h = (int*)smem;
        for (int i = tid; i < N; i += 256) h[i] = 0;
        __syncthreads();
        const int lo = p * C;
        const int hi = min(lo + C, E);
        const int n = hi - lo;
        if (n > 0) {
            if (((lo | E) & 3) == 0) {
                const int4* d4 = (const int4*)(dst + lo);
                int4* r4p = (int4*)(rank + lo);
                const int n4 = n >> 2;
                for (int i = tid; i < n4; i += 256) {
                    int4 d = d4[i];
                    int4 r;
                    r.x = atomicAdd(&h[d.x], 1);
                    r.y = atomicAdd(&h[d.y], 1);
                    r.z = atomicAdd(&h[d.z], 1);
                    r.w = atomicAdd(&h[d.w], 1);
                    r4p[i] = r;
                }
                for (int i = lo + (n4 << 2) + tid; i < hi; i += 256)
                    rank[i] = atomicAdd(&h[dst[i]], 1);
            } else {
                for (int i = lo + tid; i < hi; i += 256)
                    rank[i] = atomicAdd(&h[dst[i]], 1);
            }
        }
        __syncthreads();
        for (int i = tid; i < N; i += 256) bh[p * N + i] = h[i];
        return;
    }

    // ---- GEMM partition ----
    const int gw = wi - 1;            // 0=Q, 1=K, 2=V, 3=R
    const int row0 = blockIdx.x * 64;
    unsigned short (*As)[136] = (unsigned short(*)[136])smem;            // 64 rows
    unsigned short (*Ws)[136] = (unsigned short(*)[136])(smem + 64 * 272);// 128 rows (W^T)

    #pragma unroll
    for (int i = 0; i < 8; ++i) {
        const int idx = tid + i * 256;           // 0..2047 float4s
        const int r = idx >> 5, c4 = idx & 31;
        const int gr = row0 + r;
        float4 v = make_float4(0.f, 0.f, 0.f, 0.f);
        if (gr < N) v = *reinterpret_cast<const float4*>(&nodes[(size_t)gr * FDIM + c4 * 4]);
        ushort4 o;
        o.x = f2bf(v.x); o.y = f2bf(v.y); o.z = f2bf(v.z); o.w = f2bf(v.w);
        *reinterpret_cast<ushort4*>(&As[r][c4 * 4]) = o;
    }
    const unsigned short* Wg = &Wt[(size_t)gw * 16384];
    #pragma unroll
    for (int i = 0; i < 8; ++i) {
        const int idx = tid + i * 256;           // 0..2047
        const int r = idx >> 4, ch = idx & 15;
        const uint4 v = *reinterpret_cast<const uint4*>(&Wg[r * 128 + ch * 8]);
        *reinterpret_cast<uint4*>(&Ws[r][ch * 8]) = v;
    }
    __syncthreads();

    const int w = tid >> 6;           // wave 0..3 -> rows w*16..
    const int l = tid & 63;
    const int lr = l & 15;
    const int lh = l >> 4;

    f32x4 acc[8];
    #pragma unroll
    for (int ct = 0; ct < 8; ++ct) acc[ct] = (f32x4){0.f, 0.f, 0.f, 0.f};

    #pragma unroll
    for (int kc = 0; kc < 4; ++kc) {
        const bf16x8 a = *reinterpret_cast<const bf16x8*>(&As[w * 16 + lr][kc * 32 + lh * 8]);
        #pragma unroll
        for (int ct = 0; ct < 8; ++ct) {
            const bf16x8 bb = *reinterpret_cast<const bf16x8*>(&Ws[ct * 16 + lr][kc * 32 + lh * 8]);
            acc[ct] = __builtin_amdgcn_mfma_f32_16x16x32_bf16(a, bb, acc[ct], 0, 0, 0);
        }
    }

    const int rbase = row0 + w * 16 + lh * 4;
    #pragma unroll
    for (int ct = 0; ct < 8; ++ct) {
        const int col = ct * 16 + lr;
        float bc = 0.f;
        if (gw == 3) bc = br[col];
        #pragma unroll
        for (int r = 0; r < 4; ++r) {
            const int row = rbase + r;
            if (row >= N) continue;
            const float val = acc[ct][r];
            if (gw == 0)      Qu[(size_t)row * 128 + col] = f2bf(val);
            else if (gw == 1) KVu[(size_t)row * 256 + col] = f2bf(val);
            else if (gw == 2) KVu[(size_t)row * 256 + 128 + col] = f2bf(val);
            else              Rb[(size_t)row * 128 + col] = val + bc;
        }
    }
}

// ---------------------------------------------------------------------------
// K2a: deg[d] = sum_p bh[p][d]
// ---------------------------------------------------------------------------
__global__ __launch_bounds__(256) void deg_kernel(
    const int* __restrict__ bh, int* __restrict__ deg, int N)
{
    const int d = blockIdx.x * 256 + threadIdx.x;
    if (d < N) {
        int s = 0;
        #pragma unroll
        for (int p = 0; p < NP; ++p) s += bh[p * N + d];
        deg[d] = s;
    }
}

// ---------------------------------------------------------------------------
// K2b: single-block exclusive scan of deg -> rowptr (shuffle scan, 2 barriers)
// ---------------------------------------------------------------------------
__global__ __launch_bounds__(1024) void scan_kernel(
    const int* __restrict__ deg, int* __restrict__ rowptr, int N)
{
    __shared__ int tot[NMAX];
    __shared__ int wsum[16];
    const int tid = threadIdx.x;
    const int lane = tid & 63;
    const int wid = tid >> 6;

    for (int d = tid; d < N; d += 1024) tot[d] = deg[d];
    __syncthreads();

    const int CH = (N + 1023) / 1024;
    const int b = tid * CH;
    const int e = min(b + CH, N);
    int s = 0;
    for (int i = b; i < e; ++i) s += tot[i];

    int incl = s;
    #pragma unroll
    for (int off = 1; off < 64; off <<= 1) {
        int t = __shfl_up(incl, off);
        if (lane >= off) incl += t;
    }
    if (lane == 63) wsum[wid] = incl;
    __syncthreads();
    if (wid == 0) {
        int v = (lane < 16) ? wsum[lane] : 0;
        #pragma unroll
        for (int off = 1; off < 16; off <<= 1) {
            int t = __shfl_up(v, off);
            if (lane >= off) v += t;
        }
        if (lane < 16) wsum[lane] = v;
    }
    __syncthreads();
    const int wbase = (wid > 0) ? wsum[wid - 1] : 0;
    int run = wbase + incl - s;
    for (int i = b; i < e; ++i) {
        const int t = tot[i];
        rowptr[i] = run;
        run += t;
    }
    if (tid == 1023) rowptr[N] = wsum[15];
}

// ---------------------------------------------------------------------------
// K2c: bh counts -> per-partition ABSOLUTE exclusive bases, in place.
// ---------------------------------------------------------------------------
__global__ __launch_bounds__(256) void base_kernel(
    int* __restrict__ bh, const int* __restrict__ rowptr, int N)
{
    const int d = blockIdx.x * 256 + threadIdx.x;
    if (d < N) {
        int c = rowptr[d];
        #pragma unroll
        for (int p = 0; p < NP; ++p) {
            const int cnt = bh[p * N + d];
            bh[p * N + d] = c;
            c += cnt;
        }
    }
}

// ---------------------------------------------------------------------------
// K3: cursor-free scatter: ssrc[base[p][d] + rank[e]] = src[e].
// 8 sub-blocks per partition; one random load per edge; no atomics.
// ---------------------------------------------------------------------------
__global__ __launch_bounds__(256) void scatter_kernel(
    const int* __restrict__ src, const int* __restrict__ dst,
    const int* __restrict__ rank, const int* __restrict__ base,
    int* __restrict__ ssrc, int N, int E, int C)
{
    const int p = blockIdx.x >> 3;
    const int sub = blockIdx.x & 7;
    const int CS = C >> 3;                       // C mult of 32 -> CS mult of 4
    const int lo = p * C + sub * CS;
    const int hi = min(lo + CS, E);
    const int n = hi - lo;
    if (n <= 0) return;
    const int* bp = &base[p * N];

    if (((lo | E) & 3) == 0) {
        const int4* s4 = (const int4*)(src + lo);
        const int4* d4 = (const int4*)(dst + lo);
        const int4* r4 = (const int4*)(rank + lo);
        const int n4 = n >> 2;
        for (int i = threadIdx.x; i < n4; i += 256) {
            const int4 s = s4[i];
            const int4 d = d4[i];
            const int4 r = r4[i];
            ssrc[bp[d.x] + r.x] = s.x;
            ssrc[bp[d.y] + r.y] = s.y;
            ssrc[bp[d.z] + r.z] = s.z;
            ssrc[bp[d.w] + r.w] = s.w;
        }
        for (int i = lo + (n4 << 2) + threadIdx.x; i < hi; i += 256)
            ssrc[bp[dst[i]] + rank[i]] = src[i];
    } else {
        for (int i = lo + threadIdx.x; i < hi; i += 256)
            ssrc[bp[dst[i]] + rank[i]] = src[i];
    }
}

// ---------------------------------------------------------------------------
// K4: EDGE-SPLIT agg. Two quarter-waves per node (s=0: first half of 4-edge
// batches; s=1: second half + scalar tail), LDS partial-sum merge, s=0 does
// residual + LayerNorm. Block = 8 nodes x 2 splits x 16 lanes; grid = N/8.
// ---------------------------------------------------------------------------
__global__ __launch_bounds__(256) void agg_kernel(
    const unsigned short* __restrict__ Qu, const unsigned short* __restrict__ KVu,
    const float* __restrict__ Rb,
    const int* __restrict__ rowptr, const int* __restrict__ ssrc,
    const float* __restrict__ gamma, const float* __restrict__ beta,
    float* __restrict__ out, int N)
{
    __shared__ float sA[8][16][8];
    __shared__ float sL[8][16];

    const int wave = threadIdx.x >> 6;
    const int lane = threadIdx.x & 63;
    const int qtr = lane >> 4;
    const int lq = lane & 15;
    const int slot = wave * 2 + (qtr >> 1);
    const int s = qtr & 1;
    const int n = blockIdx.x * 8 + slot;
    const bool active = (n < N);
    const int d0 = lq * 8;

    uint4 qu = make_uint4(0u, 0u, 0u, 0u);
    int beg = 0, end = 0;
    if (active) {
        qu = *reinterpret_cast<const uint4*>(&Qu[(size_t)n * 128 + d0]);
        beg = rowptr[n];
        end = rowptr[n + 1];
    }
    const float qf0 = __uint_as_float(qu.x << 16), qf1 = __uint_as_float(qu.x & 0xFFFF0000u);
    const float qf2 = __uint_as_float(qu.y << 16), qf3 = __uint_as_float(qu.y & 0xFFFF0000u);
    const float qf4 = __uint_as_float(qu.z << 16), qf5 = __uint_as_float(qu.z & 0xFFFF0000u);
    const float qf6 = __uint_as_float(qu.w << 16), qf7 = __uint_as_float(qu.w & 0xFFFF0000u);

    const int nbAll = (end - beg) >> 2;
    const int nbh = (nbAll + 1) >> 1;
    const int b0 = (s == 0) ? 0 : nbh;
    const int b1 = (s == 0) ? nbh : nbAll;
    const int j0 = beg + b0 * 4;
    const int m = b1 - b0;

    float4 A0a = make_float4(0.f, 0.f, 0.f, 0.f), A0b = A0a;
    float4 A1a = A0a, A1b = A0a, A2a = A0a, A2b = A0a, A3a = A0a, A3b = A0a;
    float L0 = 0.f, L1 = 0.f, L2 = 0.f, L3 = 0.f;

#define GATHER(S, NK, NV)                                                     \
    {                                                                         \
        const unsigned short* bp = &KVu[(size_t)(S) * 256 + d0];              \
        NK = *reinterpret_cast<const uint4*>(bp);                             \
        NV = *reinterpret_cast<const uint4*>(bp + 128);                       \
    }
#define STEP(KU, VU, Aa, Ab, L)                                               \
    {                                                                         \
        const float k0 = __uint_as_float((KU).x << 16), k1 = __uint_as_float((KU).x & 0xFFFF0000u); \
        const float k2 = __uint_as_float((KU).y << 16), k3 = __uint_as_float((KU).y & 0xFFFF0000u); \
        const float k4 = __uint_as_float((KU).z << 16), k5 = __uint_as_float((KU).z & 0xFFFF0000u); \
        const float k6 = __uint_as_float((KU).w << 16), k7 = __uint_as_float((KU).w & 0xFFFF0000u); \
        float p = qf0 * k0 + qf1 * k1 + qf2 * k2 + qf3 * k3                   \
                + qf4 * k4 + qf5 * k5 + qf6 * k6 + qf7 * k7;                  \
        p += __shfl_xor(p, 1);                                                \
        p += __shfl_xor(p, 2);                                                \
        const float e1 = exp2f(p * SC2);                                      \
        const float v0 = __uint_as_float((VU).x << 16), v1 = __uint_as_float((VU).x & 0xFFFF0000u); \
        const float v2 = __uint_as_float((VU).y << 16), v3 = __uint_as_float((VU).y & 0xFFFF0000u); \
        const float v4 = __uint_as_float((VU).z << 16), v5 = __uint_as_float((VU).z & 0xFFFF0000u); \
        const float v6 = __uint_as_float((VU).w << 16), v7 = __uint_as_float((VU).w & 0xFFFF0000u); \
        Aa.x += e1 * v0; Aa.y += e1 * v1; Aa.z += e1 * v2; Aa.w += e1 * v3;   \
        Ab.x += e1 * v4; Ab.y += e1 * v5; Ab.z += e1 * v6; Ab.w += e1 * v7;   \
        L += e1;                                                              \
    }

    uint4 nk0, nv0, nk1, nv1, nk2, nv2, nk3, nv3;
    if (m > 0) {
        int c0i = ssrc[j0], c1i = ssrc[j0 + 1], c2i = ssrc[j0 + 2], c3i = ssrc[j0 + 3];
        GATHER(c0i, nk0, nv0); GATHER(c1i, nk1, nv1);
        GATHER(c2i, nk2, nv2); GATHER(c3i, nk3, nv3);
        int x0 = ssrc[j0 + 4], x1 = ssrc[j0 + 5], x2 = ssrc[j0 + 6], x3 = ssrc[j0 + 7];
        for (int bi = 1; bi < m; ++bi) {
            const uint4 ck0 = nk0, cv0 = nv0, ck1 = nk1, cv1 = nv1;
            const uint4 ck2 = nk2, cv2 = nv2, ck3 = nk3, cv3 = nv3;
            c0i = x0; c1i = x1; c2i = x2; c3i = x3;
            const int nbase = j0 + (bi + 1) * 4;
            x0 = ssrc[nbase]; x1 = ssrc[nbase + 1];
            x2 = ssrc[nbase + 2]; x3 = ssrc[nbase + 3];
            GATHER(c0i, nk0, nv0); GATHER(c1i, nk1, nv1);
            GATHER(c2i, nk2, nv2); GATHER(c3i, nk3, nv3);
            STEP(ck0, cv0, A0a, A0b, L0);
            STEP(ck1, cv1, A1a, A1b, L1);
            STEP(ck2, cv2, A2a, A2b, L2);
            STEP(ck3, cv3, A3a, A3b, L3);
        }
        STEP(nk0, nv0, A0a, A0b, L0);
        STEP(nk1, nv1, A1a, A1b, L1);
        STEP(nk2, nv2, A2a, A2b, L2);
        STEP(nk3, nv3, A3a, A3b, L3);
    }
    if (s == 1) {
        for (int j = beg + nbAll * 4; j < end; ++j) {
            const int s0 = ssrc[j];
            uint4 k0u, v0u;
            GATHER(s0, k0u, v0u);
            STEP(k0u, v0u, A0a, A0b, L0);
        }
    }
#undef GATHER
#undef STEP

    float a0 = (A0a.x + A1a.x) + (A2a.x + A3a.x);
    float a1 = (A0a.y + A1a.y) + (A2a.y + A3a.y);
    float a2 = (A0a.z + A1a.z) + (A2a.z + A3a.z);
    float a3 = (A0a.w + A1a.w) + (A2a.w + A3a.w);
    float a4 = (A0b.x + A1b.x) + (A2b.x + A3b.x);
    float a5 = (A0b.y + A1b.y) + (A2b.y + A3b.y);
    float a6 = (A0b.z + A1b.z) + (A2b.z + A3b.z);
    float a7 = (A0b.w + A1b.w) + (A2b.w + A3b.w);
    float L = (L0 + L1) + (L2 + L3);

    if (s == 1) {
        float* dp = &sA[slot][lq][0];
        dp[0] = a0; dp[1] = a1; dp[2] = a2; dp[3] = a3;
        dp[4] = a4; dp[5] = a5; dp[6] = a6; dp[7] = a7;
        sL[slot][lq] = L;
    }
    __syncthreads();
    if (s == 1 || !active) return;

    {
        const float* dp = &sA[slot][lq][0];
        a0 += dp[0]; a1 += dp[1]; a2 += dp[2]; a3 += dp[3];
        a4 += dp[4]; a5 += dp[5]; a6 += dp[6]; a7 += dp[7];
        L += sL[slot][lq];
    }

    const float inv = 1.f / (L + 1e-12f);          // empty segment -> x = r
    const float4 ra = *reinterpret_cast<const float4*>(&Rb[(size_t)n * 128 + d0]);
    const float4 rb = *reinterpret_cast<const float4*>(&Rb[(size_t)n * 128 + d0 + 4]);
    float xa0 = a0 * inv + ra.x;
    float xa1 = a1 * inv + ra.y;
    float xa2 = a2 * inv + ra.z;
    float xa3 = a3 * inv + ra.w;
    float xb0 = a4 * inv + rb.x;
    float xb1 = a5 * inv + rb.y;
    float xb2 = a6 * inv + rb.z;
    float xb3 = a7 * inv + rb.w;

    float s1v = (xa0 + xa1 + xa2 + xa3) + (xb0 + xb1 + xb2 + xb3);
    float s2v = xa0 * xa0 + xa1 * xa1 + xa2 * xa2 + xa3 * xa3
              + xb0 * xb0 + xb1 * xb1 + xb2 * xb2 + xb3 * xb3;
    #pragma unroll
    for (int off = 8; off; off >>= 1) {
        s1v += __shfl_xor(s1v, off);
        s2v += __shfl_xor(s2v, off);
    }
    const float mu = s1v * (1.f / 128.f);
    float var = s2v * (1.f / 128.f) - mu * mu;
    var = fmaxf(var, 0.f);
    const float rs = rsqrtf(var + LN_EPS);

    const float4 ga = *reinterpret_cast<const float4*>(&gamma[d0]);
    const float4 gb = *reinterpret_cast<const float4*>(&gamma[d0 + 4]);
    const float4 ba = *reinterpret_cast<const float4*>(&beta[d0]);
    const float4 bb = *reinterpret_cast<const float4*>(&beta[d0 + 4]);
    float4 oa, ob;
    oa.x = ga.x * (xa0 - mu) * rs + ba.x;
    oa.y = ga.y * (xa1 - mu) * rs + ba.y;
    oa.z = ga.z * (xa2 - mu) * rs + ba.z;
    oa.w = ga.w * (xa3 - mu) * rs + ba.w;
    ob.x = gb.x * (xb0 - mu) * rs + bb.x;
    ob.y = gb.y * (xb1 - mu) * rs + bb.y;
    ob.z = gb.z * (xb2 - mu) * rs + bb.z;
    ob.w = gb.w * (xb3 - mu) * rs + bb.w;
    *reinterpret_cast<float4*>(&out[(size_t)n * 128 + d0]) = oa;
    *reinterpret_cast<float4*>(&out[(size_t)n * 128 + d0 + 4]) = ob;
}

// ---------------------------------------------------------------------------
extern "C" void kernel_launch(void* const* d_in, const int* in_sizes, int n_in,
                              void* d_out, int out_size, void* d_ws, size_t ws_size,
                              hipStream_t stream)
{
    const float* nodes = (const float*)d_in[0];
    const float* W_Q   = (const float*)d_in[1];
    const float* W_K   = (const float*)d_in[2];
    const float* W_V   = (const float*)d_in[3];
    const float* W_res = (const float*)d_in[4];
    const float* b_res = (const float*)d_in[5];
    const float* gamma = (const float*)d_in[6];
    const float* beta  = (const float*)d_in[7];
    const int*   eidx  = (const int*)d_in[8];

    const int N = in_sizes[0] / FDIM;
    const int E = in_sizes[8] / 2;
    const int* src = eidx;
    const int* dst = eidx + E;

    float* out = (float*)d_out;

    // workspace carve
    unsigned short* KVu = (unsigned short*)d_ws;              // N*256 bf16
    unsigned short* Qu  = KVu + (size_t)N * 256;              // N*128 bf16
    unsigned short* Wt  = Qu + (size_t)N * 128;               // 4*128*128 bf16
    float* Rb   = (float*)(Wt + 4 * 16384);                   // N*128 f32
    int* bh     = (int*)(Rb + (size_t)N * 128);               // NP*N (counts -> abs bases)
    int* rowptr = bh + (size_t)NP * N;                        // N+1
    int* deg    = rowptr + (N + 1);                           // N
    int* rank   = deg + N;                                    // E
    int* ssrc   = rank + E;                                   // E + 8

    const int C = (((E + NP - 1) / NP) + 31) & ~31;           // chunk, mult of 32
    const int nG = (N + 63) / 64;
    const int nB = (N + 255) / 256;

    prep_kernel<<<16, 256, 0, stream>>>(W_Q, W_K, W_V, W_res, Wt);

    dim3 ggrid(nG, 5);                                        // y==0 -> histogram
    gemm_hist_kernel<<<ggrid, 256, 0, stream>>>(nodes, Wt, b_res,
                                                Qu, KVu, Rb, N, dst, bh, rank, E, C);
    deg_kernel<<<nB, 256, 0, stream>>>(bh, deg, N);
    scan_kernel<<<1, 1024, 0, stream>>>(deg, rowptr, N);
    base_kernel<<<nB, 256, 0, stream>>>(bh, rowptr, N);
    scatter_kernel<<<NP * 8, 256, 0, stream>>>(src, dst, rank, bh, ssrc, N, E, C);
    agg_kernel<<<(N + 7) / 8, 256, 0, stream>>>(Qu, KVu, Rb, rowptr, ssrc,
                                                gamma, beta, out, N);
}